// Round 12
// baseline (117.422 us; speedup 1.0000x reference)
//
#include <hip/hip_runtime.h>

// ---------------- problem constants ----------------
#define NB    1024
#define NN    19
#define NF    8
#define CCH   152         // NN*NF
#define TLEN  512
#define TP    128
#define GO    16
#define KFLAT 38912       // reference flat K (n*2048 + t*16 + o)
#define HID   128
#define NCLS  2
#define NROWS (NB*TP)     // 131072 (b,t) rows
#define KC    152         // conv channels (j,f)
#define KP    160         // padded K for mix (5*32)
#define NJP   20          // H j-planes (19 + zero pad)
#define NOUT  304         // NN*GO
#define GW    320         // g2 padded row width
#define KW    (TP*GW)     // 40960: FC1 K in permuted order

// FC1 GEMM split-K
#define KTILE 1024
#define NKT   (KW / KTILE)   // 40

typedef float  f32x4  __attribute__((ext_vector_type(4)));
typedef __bf16 bf16x8 __attribute__((ext_vector_type(8)));
typedef __bf16 bf16x4 __attribute__((ext_vector_type(4)));
typedef unsigned short u16x8 __attribute__((ext_vector_type(8)));

// ---------------------------------------------------------------------------
// P1: softmax(adj) + fused BN affine (1 block)
// ---------------------------------------------------------------------------
__global__ __launch_bounds__(256) void prep_small(
    const float* __restrict__ adj,
    const float* __restrict__ bn_gamma, const float* __restrict__ bn_beta,
    const float* __restrict__ bn_mean,  const float* __restrict__ bn_var,
    const float* __restrict__ conv_b,
    float* __restrict__ A_g, float* __restrict__ bnS, float* __restrict__ bnB)
{
    const int tid = threadIdx.x;
    if (tid < NN) {
        float v[NN];
        float m = -1e30f;
        #pragma unroll
        for (int j = 0; j < NN; ++j) { v[j] = adj[tid * NN + j]; m = fmaxf(m, v[j]); }
        float s = 0.f;
        #pragma unroll
        for (int j = 0; j < NN; ++j) { v[j] = expf(v[j] - m); s += v[j]; }
        float rc = 1.f / s;
        #pragma unroll
        for (int j = 0; j < NN; ++j) A_g[tid * NN + j] = v[j] * rc;
    }
    if (tid >= 64 && tid < 64 + CCH) {
        int c = tid - 64;
        float inv = bn_gamma[c] * rsqrtf(bn_var[c] + 1e-5f);
        bnS[c] = inv;
        bnB[c] = conv_b[c] * inv + bn_beta[c] - bn_mean[c] * inv;
    }
}

// ---------------------------------------------------------------------------
// P2: Kronecker matrix m2g[c][k] = A[n,j]*gcn_w[o,f], c=(n*16+o) in [0,320)
// ---------------------------------------------------------------------------
__global__ __launch_bounds__(256) void prep_m2(
    const float* __restrict__ A_g, const float* __restrict__ gcn_w,
    __bf16* __restrict__ m2g)
{
    int i = blockIdx.x * 256 + threadIdx.x;
    if (i >= GW * KP) return;
    int c = i / KP, k = i - c * KP;
    float v = 0.f;
    if (c < NOUT && k < KC) {
        int n = c >> 4, o = c & 15;
        int j = k >> 3, f = k & 7;
        v = A_g[n * NN + j] * gcn_w[o * NF + f];
    }
    m2g[i] = (__bf16)v;
}

// ---------------------------------------------------------------------------
// F: FUSED conv+bn+relu+pool + A-mix/gcn MFMA -> g2[(b,t)][320].
//    v3 (fixes R11's register-pressure occupancy limit):
//    - 10 waves/block (640 thr): wave owns 2 ct-tiles -> mf[2][5] = 40 VGPR
//      (was mf[5][5]=100) => ~20 waves/CU instead of 8.
//    - conv x reads: 3 aligned float4 loads (1KB contiguous per instr,
//      L1-deduped) instead of 9 strided scalars.
//    - conv planes: wave w -> n = 2w, 2w+1 (20 = NJP exactly).
// ---------------------------------------------------------------------------
__global__ __launch_bounds__(640) void conv_mix(
    const float* __restrict__ x,       // [NB][NN][TLEN]
    const float* __restrict__ conv_w,  // [CCH][5]
    const float* __restrict__ bnS, const float* __restrict__ bnB,
    const __bf16* __restrict__ m2g,    // [GW][KP]
    const float* __restrict__ gcn_b,   // [GO]
    __bf16* __restrict__ g2)           // [NROWS][GW]
{
    __shared__ __align__(16) __bf16 Hs[NJP][64][8];   // 20,480 B

    const int tid  = threadIdx.x;
    const int lane = tid & 63, w = tid >> 6;   // w in [0,10)
    const int b    = blockIdx.x >> 1;
    const int half = blockIdx.x & 1;
    const int tp0  = half * 64;                // pooled-t offset of this block

    // ---- phase 1: conv+bn+relu+pool -> Hs[n][lane][f]; planes 2w, 2w+1 ----
    {
        const int T = tp0 + lane;              // pooled t 0..127
        #pragma unroll
        for (int k = 0; k < 2; ++k) {
            const int n = 2 * w + k;           // wave-uniform
            if (n < NN) {
                const float* xr = x + ((size_t)b * NN + n) * TLEN;
                float4 L0 = {0.f, 0.f, 0.f, 0.f};
                float4 L2 = {0.f, 0.f, 0.f, 0.f};
                if (T > 0)   L0 = *(const float4*)(xr + 4 * T - 4);
                float4 L1 =       *(const float4*)(xr + 4 * T);
                if (T < 127) L2 = *(const float4*)(xr + 4 * T + 4);
                float xv[9] = {L0.z, L0.w, L1.x, L1.y, L1.z, L1.w, L2.x, L2.y, L2.z};

                const float* cw = conv_w + n * (NF * 5);
                const float* Sp = bnS + n * NF;
                const float* Bp = bnB + n * NF;
                union { __bf16 h[8]; u16x8 v; } hv;
                #pragma unroll
                for (int f = 0; f < NF; ++f) {
                    float w0 = cw[f*5+0], w1 = cw[f*5+1], w2 = cw[f*5+2], w3 = cw[f*5+3], w4 = cw[f*5+4];
                    float s = Sp[f], bb = Bp[f];
                    float m = -1e30f;
                    #pragma unroll
                    for (int p = 0; p < 4; ++p) {
                        float a = xv[p]*w0 + xv[p+1]*w1 + xv[p+2]*w2 + xv[p+3]*w3 + xv[p+4]*w4;
                        m = fmaxf(m, a * s + bb);
                    }
                    hv.h[f] = (__bf16)fmaxf(m, 0.f);
                }
                *(u16x8*)&Hs[n][lane][0] = hv.v;
            } else {                           // plane 19: K pad zeros
                u16x8 z = {0,0,0,0,0,0,0,0};
                *(u16x8*)&Hs[NJP - 1][lane][0] = z;
            }
        }
    }

    // ---- m2 fragments from L2 (issued before barrier; latency hides) ----
    const int arow = lane & 15;
    const int jg   = lane >> 4;            // 0..3
    const int ct0  = w * 2;                // wave's 2 ct-tiles (32 cols)
    const float4 gbv = *(const float4*)(gcn_b + jg * 4);

    bf16x8 mf[2][5];
    #pragma unroll
    for (int ct = 0; ct < 2; ++ct)
        #pragma unroll
        for (int ks = 0; ks < 5; ++ks)
            mf[ct][ks] = *(const bf16x8*)(
                m2g + (size_t)((ct0 + ct) * 16 + arow) * KP + ks * 32 + jg * 8);

    __syncthreads();

    // ---- phase 2: 4 row-tiles x (2 ct x 5 ks) MFMA, H frags from LDS ----
    for (int it = 0; it < 4; ++it) {
        const int tl = it * 16 + arow;     // local row 0..63

        bf16x8 af[5];
        #pragma unroll
        for (int ks = 0; ks < 5; ++ks)
            af[ks] = *(const bf16x8*)&Hs[ks * 4 + jg][tl][0];

        f32x4 acc[2];
        #pragma unroll
        for (int ct = 0; ct < 2; ++ct) acc[ct] = (f32x4){0.f, 0.f, 0.f, 0.f};

        #pragma unroll
        for (int ks = 0; ks < 5; ++ks)
            #pragma unroll
            for (int ct = 0; ct < 2; ++ct)
                acc[ct] = __builtin_amdgcn_mfma_f32_16x16x32_bf16(mf[ct][ks], af[ks], acc[ct], 0, 0, 0);

        // C^T: lane holds cols c = (ct0+ct)*16 + jg*4 + r, row b*128+tp0+tl
        __bf16* gp = g2 + ((size_t)b * TP + tp0 + tl) * GW + ct0 * 16 + jg * 4;
        #pragma unroll
        for (int ct = 0; ct < 2; ++ct) {
            bf16x4 v;
            v[0] = (__bf16)fmaxf(acc[ct][0] + gbv.x, 0.f);
            v[1] = (__bf16)fmaxf(acc[ct][1] + gbv.y, 0.f);
            v[2] = (__bf16)fmaxf(acc[ct][2] + gbv.z, 0.f);
            v[3] = (__bf16)fmaxf(acc[ct][3] + gbv.w, 0.f);
            *(bf16x4*)(gp + ct * 16) = v;
        }
    }
}

// ---------------------------------------------------------------------------
// W: permute+convert w1 -> w1p[j][t*320 + c] bf16 (c=(n*16+o); pad cols 0)
// ---------------------------------------------------------------------------
__global__ __launch_bounds__(256) void w1_permute(
    const float* __restrict__ w1, __bf16* __restrict__ w1p)
{
    int i = blockIdx.x * 256 + threadIdx.x;    // chunk: j*5120 + t*40 + c8
    if (i >= HID * (KW / 8)) return;
    int j = i / 5120, rem = i - j * 5120;
    int t = rem / 40, c8 = rem - t * 40;
    bf16x8 r;
    if (c8 < 38) {
        int n = c8 >> 1, o0 = (c8 & 1) * 8;
        const float* src = w1 + (size_t)j * KFLAT + n * 2048 + t * 16 + o0;
        #pragma unroll
        for (int e = 0; e < 8; ++e) r[e] = (__bf16)src[e];
    } else {
        #pragma unroll
        for (int e = 0; e < 8; ++e) r[e] = (__bf16)0.f;
    }
    *(bf16x8*)(w1p + (size_t)i * 8) = r;
}

// ---------------------------------------------------------------------------
// G: split-K bf16 MFMA GEMM: partial[kt][b][j] = sum_k g2[b][k]*w1p[j][k]
// ---------------------------------------------------------------------------
__global__ __launch_bounds__(256) void gemm_fc1(
    const __bf16* __restrict__ gmat,   // [NB][KW]
    const __bf16* __restrict__ wmat,   // [HID][KW]
    float* __restrict__ partial)       // [NKT][NB][HID]
{
    __shared__ __align__(16) __bf16 At[128][40];
    __shared__ __align__(16) __bf16 Bt[128][40];

    const int tid = threadIdx.x;
    const int b0 = blockIdx.x * 128;
    const int k0 = blockIdx.y * KTILE;

    const int lane = tid & 63;
    const int w = tid >> 6;
    const int wm = (w >> 1) * 64;
    const int wn = (w & 1) * 64;

    const int srow = tid >> 2;
    const int soct = tid & 3;

    f32x4 acc[4][4];
    #pragma unroll
    for (int m = 0; m < 4; ++m)
        #pragma unroll
        for (int n = 0; n < 4; ++n) acc[m][n] = (f32x4){0.f, 0.f, 0.f, 0.f};

    const int arow = lane & 15;
    const int aoct = (lane >> 4) * 8;

    for (int ks = 0; ks < KTILE / 32; ++ks) {
        const int gk = k0 + ks * 32 + soct * 8;
        *(u16x8*)&At[srow     ][soct * 8] = *(const u16x8*)(gmat + (size_t)(b0 + srow     ) * KW + gk);
        *(u16x8*)&At[srow + 64][soct * 8] = *(const u16x8*)(gmat + (size_t)(b0 + srow + 64) * KW + gk);
        *(u16x8*)&Bt[srow     ][soct * 8] = *(const u16x8*)(wmat + (size_t)(srow     ) * KW + gk);
        *(u16x8*)&Bt[srow + 64][soct * 8] = *(const u16x8*)(wmat + (size_t)(srow + 64) * KW + gk);
        __syncthreads();

        bf16x8 af[4], bfr[4];
        #pragma unroll
        for (int m = 0; m < 4; ++m) af[m]  = *(const bf16x8*)&At[wm + m * 16 + arow][aoct];
        #pragma unroll
        for (int n = 0; n < 4; ++n) bfr[n] = *(const bf16x8*)&Bt[wn + n * 16 + arow][aoct];
        #pragma unroll
        for (int m = 0; m < 4; ++m)
            #pragma unroll
            for (int n = 0; n < 4; ++n)
                acc[m][n] = __builtin_amdgcn_mfma_f32_16x16x32_bf16(af[m], bfr[n], acc[m][n], 0, 0, 0);
        __syncthreads();
    }

    float* pout = partial + (size_t)blockIdx.y * (NB * HID);
    #pragma unroll
    for (int m = 0; m < 4; ++m) {
        const int rbase = b0 + wm + m * 16 + (lane >> 4) * 4;
        #pragma unroll
        for (int n = 0; n < 4; ++n) {
            const int col = wn + n * 16 + (lane & 15);
            #pragma unroll
            for (int r = 0; r < 4; ++r)
                pout[(size_t)(rbase + r) * HID + col] = acc[m][n][r];
        }
    }
}

// ---------------------------------------------------------------------------
// R: reduce split-K partials + b1 + ReLU, then FC2 (128->2) + b2
// ---------------------------------------------------------------------------
__global__ __launch_bounds__(128) void reduce_fc2(
    const float* __restrict__ partial,  // [NKT][NB][HID]
    const float* __restrict__ b1,
    const float* __restrict__ w2,       // [NCLS][HID]
    const float* __restrict__ b2,
    float* __restrict__ out)            // [NB][NCLS]
{
    __shared__ float red0[128], red1[128];
    const int b = blockIdx.x, j = threadIdx.x;
    float s = b1[j];
    #pragma unroll 4
    for (int p = 0; p < NKT; ++p) s += partial[(size_t)p * (NB * HID) + b * HID + j];
    float h = fmaxf(s, 0.f);
    red0[j] = h * w2[j];
    red1[j] = h * w2[HID + j];
    __syncthreads();
    for (int off = 64; off > 0; off >>= 1) {
        if (j < off) { red0[j] += red0[j + off]; red1[j] += red1[j + off]; }
        __syncthreads();
    }
    if (j == 0) {
        out[b * 2 + 0] = red0[0] + b2[0];
        out[b * 2 + 1] = red1[0] + b2[1];
    }
}

// ---------------------------------------------------------------------------
extern "C" void kernel_launch(void* const* d_in, const int* in_sizes, int n_in,
                              void* d_out, int out_size, void* d_ws, size_t ws_size,
                              hipStream_t stream) {
    const float* x        = (const float*)d_in[0];
    const float* conv_w   = (const float*)d_in[1];
    const float* conv_b   = (const float*)d_in[2];
    const float* bn_gamma = (const float*)d_in[3];
    const float* bn_beta  = (const float*)d_in[4];
    const float* bn_mean  = (const float*)d_in[5];
    const float* bn_var   = (const float*)d_in[6];
    const float* adj      = (const float*)d_in[7];
    const float* gcn_w    = (const float*)d_in[8];
    const float* gcn_b    = (const float*)d_in[9];
    const float* w1       = (const float*)d_in[10];
    const float* b1       = (const float*)d_in[11];
    const float* w2       = (const float*)d_in[12];
    const float* b2       = (const float*)d_in[13];
    float* out = (float*)d_out;

    // workspace:
    //   g2   [0,           83,886,080)   conv_mix -> gemm_fc1
    //   w1p  [83,886,080,  94,371,840)   w1_permute -> gemm
    //   part [94,371,840, 115,343,360)   gemm -> reduce
    //   m2g  [125,829,120, 125,931,520)  prep_m2 -> conv_mix
    //   A_g/bnS/bnB after that
    char* ws = (char*)d_ws;
    __bf16* g2   = (__bf16*)ws;
    __bf16* w1p  = (__bf16*)(ws + 83886080);
    float*  part = (float*)(ws + 94371840);
    __bf16* m2g  = (__bf16*)(ws + 125829120);
    float*  A_g  = (float*)(ws + 125931520);
    float*  bnS  = (float*)(ws + 125933568);
    float*  bnB  = (float*)(ws + 125934592);

    prep_small<<<dim3(1), dim3(256), 0, stream>>>(
        adj, bn_gamma, bn_beta, bn_mean, bn_var, conv_b, A_g, bnS, bnB);
    prep_m2<<<dim3(200), dim3(256), 0, stream>>>(A_g, gcn_w, m2g);
    conv_mix<<<dim3(NB * 2), dim3(640), 0, stream>>>(x, conv_w, bnS, bnB, m2g, gcn_b, g2);
    w1_permute<<<dim3(HID * (KW / 8) / 256), dim3(256), 0, stream>>>(w1, w1p);
    gemm_fc1<<<dim3(8, NKT), dim3(256), 0, stream>>>(g2, w1p, part);
    reduce_fc2<<<dim3(NB), dim3(128), 0, stream>>>(part, b1, w2, b2, out);
}

// Round 13
// 115.597 us; speedup vs baseline: 1.0158x; 1.0158x over previous
//
#include <hip/hip_runtime.h>

// ---------------- problem constants ----------------
#define NB    1024
#define NN    19
#define NF    8
#define CCH   152         // NN*NF
#define TLEN  512
#define TP    128
#define GO    16
#define KFLAT 38912       // reference flat K (n*2048 + t*16 + o)
#define HID   128
#define NCLS  2
#define NROWS (NB*TP)     // 131072 (b,t) rows
#define KC    152         // conv channels (j,f)
#define KP    160         // padded K for mix (5*32)
#define NJP   20          // H j-planes (19 + zero pad)
#define NOUT  304         // NN*GO
#define GW    320         // g2 padded row width
#define KW    (TP*GW)     // 40960: FC1 K in permuted order
#define NTPB  4           // tiles per persistent conv_mix block

// FC1 GEMM split-K
#define KTILE 1024
#define NKT   (KW / KTILE)   // 40

typedef float  f32x4  __attribute__((ext_vector_type(4)));
typedef __bf16 bf16x8 __attribute__((ext_vector_type(8)));
typedef __bf16 bf16x4 __attribute__((ext_vector_type(4)));
typedef unsigned short u16x8 __attribute__((ext_vector_type(8)));

// ---------------------------------------------------------------------------
// P1: softmax(adj) + fused BN affine (1 block)
// ---------------------------------------------------------------------------
__global__ __launch_bounds__(256) void prep_small(
    const float* __restrict__ adj,
    const float* __restrict__ bn_gamma, const float* __restrict__ bn_beta,
    const float* __restrict__ bn_mean,  const float* __restrict__ bn_var,
    const float* __restrict__ conv_b,
    float* __restrict__ A_g, float* __restrict__ bnS, float* __restrict__ bnB)
{
    const int tid = threadIdx.x;
    if (tid < NN) {
        float v[NN];
        float m = -1e30f;
        #pragma unroll
        for (int j = 0; j < NN; ++j) { v[j] = adj[tid * NN + j]; m = fmaxf(m, v[j]); }
        float s = 0.f;
        #pragma unroll
        for (int j = 0; j < NN; ++j) { v[j] = expf(v[j] - m); s += v[j]; }
        float rc = 1.f / s;
        #pragma unroll
        for (int j = 0; j < NN; ++j) A_g[tid * NN + j] = v[j] * rc;
    }
    if (tid >= 64 && tid < 64 + CCH) {
        int c = tid - 64;
        float inv = bn_gamma[c] * rsqrtf(bn_var[c] + 1e-5f);
        bnS[c] = inv;
        bnB[c] = conv_b[c] * inv + bn_beta[c] - bn_mean[c] * inv;
    }
}

// ---------------------------------------------------------------------------
// P2: Kronecker matrix m2g[c][k] = A[n,j]*gcn_w[o,f], c=(n*16+o) in [0,320)
// ---------------------------------------------------------------------------
__global__ __launch_bounds__(256) void prep_m2(
    const float* __restrict__ A_g, const float* __restrict__ gcn_w,
    __bf16* __restrict__ m2g)
{
    int i = blockIdx.x * 256 + threadIdx.x;
    if (i >= GW * KP) return;
    int c = i / KP, k = i - c * KP;
    float v = 0.f;
    if (c < NOUT && k < KC) {
        int n = c >> 4, o = c & 15;
        int j = k >> 3, f = k & 7;
        v = A_g[n * NN + j] * gcn_w[o * NF + f];
    }
    m2g[i] = (__bf16)v;
}

// ---------------------------------------------------------------------------
// F: FUSED conv+bn+relu+pool + A-mix/gcn MFMA -> g2[(b,t)][320].
//    v4 (fixes R12's latency exposure): PERSISTENT blocks, 4 tiles each,
//    double-buffered Hs, software pipeline:
//      loadx(i+1) issued -> MIX(i) MFMAs hide the HBM latency -> CONV(i+1)
//      into other buffer -> 1 barrier.
//    mf[2][5] (40 VGPR) loaded once per block; plane-0 x prefetched in regs
//    (12 VGPR) to keep peak VGPR ~100 (2 blocks/CU co-resident).
// ---------------------------------------------------------------------------
__global__ __launch_bounds__(640) void conv_mix(
    const float* __restrict__ x,       // [NB][NN][TLEN]
    const float* __restrict__ conv_w,  // [CCH][5]
    const float* __restrict__ bnS, const float* __restrict__ bnB,
    const __bf16* __restrict__ m2g,    // [GW][KP]
    const float* __restrict__ gcn_b,   // [GO]
    __bf16* __restrict__ g2)           // [NROWS][GW]
{
    __shared__ __align__(16) __bf16 Hs[2][NJP][64][8];   // 40,960 B

    const int tid  = threadIdx.x;
    const int lane = tid & 63, w = tid >> 6;   // w in [0,10)
    const int arow = lane & 15;
    const int jg   = lane >> 4;                // 0..3
    const int ct0  = w * 2;                    // wave's 2 ct-tiles
    const float4 gbv = *(const float4*)(gcn_b + jg * 4);
    const int n0 = 2 * w, n1 = 2 * w + 1;      // wave's conv planes

    const int t0 = blockIdx.x * NTPB;          // first tile (tau = b*2+half)

    // ---- m2 fragments once per block (L2-resident source) ----
    bf16x8 mf[2][5];
    #pragma unroll
    for (int ct = 0; ct < 2; ++ct)
        #pragma unroll
        for (int ks = 0; ks < 5; ++ks)
            mf[ct][ks] = *(const bf16x8*)(
                m2g + (size_t)((ct0 + ct) * 16 + arow) * KP + ks * 32 + jg * 8);

    float4 nx[3];                              // plane-0 prefetch regs
    const float4 f4z = {0.f, 0.f, 0.f, 0.f};

    // plane-0 x loads for tile tau -> nx
    auto LOADX = [&](int tau) {
        const int b = tau >> 1;
        const int T = (tau & 1) * 64 + lane;
        const float* xr = x + ((size_t)b * NN + n0) * TLEN;
        nx[0] = (T > 0)   ? *(const float4*)(xr + 4 * T - 4) : f4z;
        nx[1] =             *(const float4*)(xr + 4 * T);
        nx[2] = (T < 127) ? *(const float4*)(xr + 4 * T + 4) : f4z;
    };

    // conv one plane from 3 float4 regs -> Hs[buf][n][lane]
    auto CONV1 = [&](int buf, int n, const float4& L0, const float4& L1, const float4& L2) {
        float xv[9] = {L0.z, L0.w, L1.x, L1.y, L1.z, L1.w, L2.x, L2.y, L2.z};
        const float* cw = conv_w + n * (NF * 5);
        const float* Sp = bnS + n * NF;
        const float* Bp = bnB + n * NF;
        union { __bf16 h[8]; u16x8 v; } hv;
        #pragma unroll
        for (int f = 0; f < NF; ++f) {
            float w0 = cw[f*5+0], w1 = cw[f*5+1], w2 = cw[f*5+2], w3 = cw[f*5+3], w4 = cw[f*5+4];
            float s = Sp[f], bb = Bp[f];
            float m = -1e30f;
            #pragma unroll
            for (int p = 0; p < 4; ++p) {
                float a = xv[p]*w0 + xv[p+1]*w1 + xv[p+2]*w2 + xv[p+3]*w3 + xv[p+4]*w4;
                m = fmaxf(m, a * s + bb);
            }
            hv.h[f] = (__bf16)fmaxf(m, 0.f);
        }
        *(u16x8*)&Hs[buf][n][lane][0] = hv.v;
    };

    // conv both planes of this wave for tile tau into Hs[buf]
    auto CONV = [&](int buf, int tau) {
        const int b = tau >> 1;
        const int T = (tau & 1) * 64 + lane;
        CONV1(buf, n0, nx[0], nx[1], nx[2]);           // plane n0 from prefetch
        if (n1 < NN) {                                  // plane n1 direct
            const float* xr = x + ((size_t)b * NN + n1) * TLEN;
            float4 L0 = (T > 0)   ? *(const float4*)(xr + 4 * T - 4) : f4z;
            float4 L1 =             *(const float4*)(xr + 4 * T);
            float4 L2 = (T < 127) ? *(const float4*)(xr + 4 * T + 4) : f4z;
            CONV1(buf, n1, L0, L1, L2);
        } else {                                        // plane 19: K pad zeros
            u16x8 z = {0,0,0,0,0,0,0,0};
            *(u16x8*)&Hs[buf][NJP - 1][lane][0] = z;
        }
    };

    // MFMA mix of tile tau from Hs[buf] -> g2
    auto MIX = [&](int buf, int tau) {
        const int b = tau >> 1, tp0 = (tau & 1) * 64;
        for (int it = 0; it < 4; ++it) {
            const int tl = it * 16 + arow;
            bf16x8 af[5];
            #pragma unroll
            for (int ks = 0; ks < 5; ++ks)
                af[ks] = *(const bf16x8*)&Hs[buf][ks * 4 + jg][tl][0];
            f32x4 acc[2];
            #pragma unroll
            for (int ct = 0; ct < 2; ++ct) acc[ct] = (f32x4){0.f, 0.f, 0.f, 0.f};
            #pragma unroll
            for (int ks = 0; ks < 5; ++ks)
                #pragma unroll
                for (int ct = 0; ct < 2; ++ct)
                    acc[ct] = __builtin_amdgcn_mfma_f32_16x16x32_bf16(mf[ct][ks], af[ks], acc[ct], 0, 0, 0);
            __bf16* gp = g2 + ((size_t)b * TP + tp0 + tl) * GW + ct0 * 16 + jg * 4;
            #pragma unroll
            for (int ct = 0; ct < 2; ++ct) {
                bf16x4 v;
                v[0] = (__bf16)fmaxf(acc[ct][0] + gbv.x, 0.f);
                v[1] = (__bf16)fmaxf(acc[ct][1] + gbv.y, 0.f);
                v[2] = (__bf16)fmaxf(acc[ct][2] + gbv.z, 0.f);
                v[3] = (__bf16)fmaxf(acc[ct][3] + gbv.w, 0.f);
                *(bf16x4*)(gp + ct * 16) = v;
            }
        }
    };

    // ---- pipeline: prologue ----
    LOADX(t0);
    CONV(0, t0);
    __syncthreads();

    // ---- steady state: loadx(i+1) || mix(i) ; conv(i+1) ; barrier ----
    for (int i = 0; i < NTPB; ++i) {
        if (i + 1 < NTPB) LOADX(t0 + i + 1);
        MIX(i & 1, t0 + i);
        if (i + 1 < NTPB) {
            CONV((i + 1) & 1, t0 + i + 1);
            __syncthreads();
        }
    }
}

// ---------------------------------------------------------------------------
// W: permute+convert w1 -> w1p[j][t*320 + c] bf16 (c=(n*16+o); pad cols 0)
// ---------------------------------------------------------------------------
__global__ __launch_bounds__(256) void w1_permute(
    const float* __restrict__ w1, __bf16* __restrict__ w1p)
{
    int i = blockIdx.x * 256 + threadIdx.x;    // chunk: j*5120 + t*40 + c8
    if (i >= HID * (KW / 8)) return;
    int j = i / 5120, rem = i - j * 5120;
    int t = rem / 40, c8 = rem - t * 40;
    bf16x8 r;
    if (c8 < 38) {
        int n = c8 >> 1, o0 = (c8 & 1) * 8;
        const float* src = w1 + (size_t)j * KFLAT + n * 2048 + t * 16 + o0;
        #pragma unroll
        for (int e = 0; e < 8; ++e) r[e] = (__bf16)src[e];
    } else {
        #pragma unroll
        for (int e = 0; e < 8; ++e) r[e] = (__bf16)0.f;
    }
    *(bf16x8*)(w1p + (size_t)i * 8) = r;
}

// ---------------------------------------------------------------------------
// G: split-K bf16 MFMA GEMM: partial[kt][b][j] = sum_k g2[b][k]*w1p[j][k]
// ---------------------------------------------------------------------------
__global__ __launch_bounds__(256) void gemm_fc1(
    const __bf16* __restrict__ gmat,   // [NB][KW]
    const __bf16* __restrict__ wmat,   // [HID][KW]
    float* __restrict__ partial)       // [NKT][NB][HID]
{
    __shared__ __align__(16) __bf16 At[128][40];
    __shared__ __align__(16) __bf16 Bt[128][40];

    const int tid = threadIdx.x;
    const int b0 = blockIdx.x * 128;
    const int k0 = blockIdx.y * KTILE;

    const int lane = tid & 63;
    const int w = tid >> 6;
    const int wm = (w >> 1) * 64;
    const int wn = (w & 1) * 64;

    const int srow = tid >> 2;
    const int soct = tid & 3;

    f32x4 acc[4][4];
    #pragma unroll
    for (int m = 0; m < 4; ++m)
        #pragma unroll
        for (int n = 0; n < 4; ++n) acc[m][n] = (f32x4){0.f, 0.f, 0.f, 0.f};

    const int arow = lane & 15;
    const int aoct = (lane >> 4) * 8;

    for (int ks = 0; ks < KTILE / 32; ++ks) {
        const int gk = k0 + ks * 32 + soct * 8;
        *(u16x8*)&At[srow     ][soct * 8] = *(const u16x8*)(gmat + (size_t)(b0 + srow     ) * KW + gk);
        *(u16x8*)&At[srow + 64][soct * 8] = *(const u16x8*)(gmat + (size_t)(b0 + srow + 64) * KW + gk);
        *(u16x8*)&Bt[srow     ][soct * 8] = *(const u16x8*)(wmat + (size_t)(srow     ) * KW + gk);
        *(u16x8*)&Bt[srow + 64][soct * 8] = *(const u16x8*)(wmat + (size_t)(srow + 64) * KW + gk);
        __syncthreads();

        bf16x8 af[4], bfr[4];
        #pragma unroll
        for (int m = 0; m < 4; ++m) af[m]  = *(const bf16x8*)&At[wm + m * 16 + arow][aoct];
        #pragma unroll
        for (int n = 0; n < 4; ++n) bfr[n] = *(const bf16x8*)&Bt[wn + n * 16 + arow][aoct];
        #pragma unroll
        for (int m = 0; m < 4; ++m)
            #pragma unroll
            for (int n = 0; n < 4; ++n)
                acc[m][n] = __builtin_amdgcn_mfma_f32_16x16x32_bf16(af[m], bfr[n], acc[m][n], 0, 0, 0);
        __syncthreads();
    }

    float* pout = partial + (size_t)blockIdx.y * (NB * HID);
    #pragma unroll
    for (int m = 0; m < 4; ++m) {
        const int rbase = b0 + wm + m * 16 + (lane >> 4) * 4;
        #pragma unroll
        for (int n = 0; n < 4; ++n) {
            const int col = wn + n * 16 + (lane & 15);
            #pragma unroll
            for (int r = 0; r < 4; ++r)
                pout[(size_t)(rbase + r) * HID + col] = acc[m][n][r];
        }
    }
}

// ---------------------------------------------------------------------------
// R: reduce split-K partials + b1 + ReLU, then FC2 (128->2) + b2
// ---------------------------------------------------------------------------
__global__ __launch_bounds__(128) void reduce_fc2(
    const float* __restrict__ partial,  // [NKT][NB][HID]
    const float* __restrict__ b1,
    const float* __restrict__ w2,       // [NCLS][HID]
    const float* __restrict__ b2,
    float* __restrict__ out)            // [NB][NCLS]
{
    __shared__ float red0[128], red1[128];
    const int b = blockIdx.x, j = threadIdx.x;
    float s = b1[j];
    #pragma unroll 4
    for (int p = 0; p < NKT; ++p) s += partial[(size_t)p * (NB * HID) + b * HID + j];
    float h = fmaxf(s, 0.f);
    red0[j] = h * w2[j];
    red1[j] = h * w2[HID + j];
    __syncthreads();
    for (int off = 64; off > 0; off >>= 1) {
        if (j < off) { red0[j] += red0[j + off]; red1[j] += red1[j + off]; }
        __syncthreads();
    }
    if (j == 0) {
        out[b * 2 + 0] = red0[0] + b2[0];
        out[b * 2 + 1] = red1[0] + b2[1];
    }
}

// ---------------------------------------------------------------------------
extern "C" void kernel_launch(void* const* d_in, const int* in_sizes, int n_in,
                              void* d_out, int out_size, void* d_ws, size_t ws_size,
                              hipStream_t stream) {
    const float* x        = (const float*)d_in[0];
    const float* conv_w   = (const float*)d_in[1];
    const float* conv_b   = (const float*)d_in[2];
    const float* bn_gamma = (const float*)d_in[3];
    const float* bn_beta  = (const float*)d_in[4];
    const float* bn_mean  = (const float*)d_in[5];
    const float* bn_var   = (const float*)d_in[6];
    const float* adj      = (const float*)d_in[7];
    const float* gcn_w    = (const float*)d_in[8];
    const float* gcn_b    = (const float*)d_in[9];
    const float* w1       = (const float*)d_in[10];
    const float* b1       = (const float*)d_in[11];
    const float* w2       = (const float*)d_in[12];
    const float* b2       = (const float*)d_in[13];
    float* out = (float*)d_out;

    // workspace:
    //   g2   [0,           83,886,080)   conv_mix -> gemm_fc1
    //   w1p  [83,886,080,  94,371,840)   w1_permute -> gemm
    //   part [94,371,840, 115,343,360)   gemm -> reduce
    //   m2g  [125,829,120, 125,931,520)  prep_m2 -> conv_mix
    //   A_g/bnS/bnB after that
    char* ws = (char*)d_ws;
    __bf16* g2   = (__bf16*)ws;
    __bf16* w1p  = (__bf16*)(ws + 83886080);
    float*  part = (float*)(ws + 94371840);
    __bf16* m2g  = (__bf16*)(ws + 125829120);
    float*  A_g  = (float*)(ws + 125931520);
    float*  bnS  = (float*)(ws + 125933568);
    float*  bnB  = (float*)(ws + 125934592);

    prep_small<<<dim3(1), dim3(256), 0, stream>>>(
        adj, bn_gamma, bn_beta, bn_mean, bn_var, conv_b, A_g, bnS, bnB);
    prep_m2<<<dim3(200), dim3(256), 0, stream>>>(A_g, gcn_w, m2g);
    conv_mix<<<dim3(NB * 2 / NTPB), dim3(640), 0, stream>>>(x, conv_w, bnS, bnB, m2g, gcn_b, g2);
    w1_permute<<<dim3(HID * (KW / 8) / 256), dim3(256), 0, stream>>>(w1, w1p);
    gemm_fc1<<<dim3(8, NKT), dim3(256), 0, stream>>>(g2, w1p, part);
    reduce_fc2<<<dim3(NB), dim3(128), 0, stream>>>(part, b1, w2, b2, out);
}

// Round 14
// 107.594 us; speedup vs baseline: 1.0914x; 1.0744x over previous
//
#include <hip/hip_runtime.h>

// ---------------- problem constants ----------------
#define NB    1024
#define NN    19
#define NF    8
#define CCH   152         // NN*NF
#define TLEN  512
#define TP    128
#define GO    16
#define KFLAT 38912       // reference flat K (n*2048 + t*16 + o)
#define HID   128
#define NCLS  2
#define NROWS (NB*TP)     // 131072 (b,t) rows
#define KC    152         // conv channels (j,f)
#define KP    160         // padded K for mix (5*32)
#define NJP   20          // H j-planes (19 + zero pad)
#define NOUT  304         // NN*GO
#define GW    320         // g2 padded row width
#define KW    (TP*GW)     // 40960: FC1 K in permuted order

// FC1 GEMM split-K
#define KTILE 1024
#define NKT   (KW / KTILE)   // 40

typedef float  f32x4  __attribute__((ext_vector_type(4)));
typedef __bf16 bf16x8 __attribute__((ext_vector_type(8)));
typedef __bf16 bf16x4 __attribute__((ext_vector_type(4)));
typedef unsigned short u16x8 __attribute__((ext_vector_type(8)));

// ---------------------------------------------------------------------------
// P1: softmax(adj) + fused BN affine (1 block)
// ---------------------------------------------------------------------------
__global__ __launch_bounds__(256) void prep_small(
    const float* __restrict__ adj,
    const float* __restrict__ bn_gamma, const float* __restrict__ bn_beta,
    const float* __restrict__ bn_mean,  const float* __restrict__ bn_var,
    const float* __restrict__ conv_b,
    float* __restrict__ A_g, float* __restrict__ bnS, float* __restrict__ bnB)
{
    const int tid = threadIdx.x;
    if (tid < NN) {
        float v[NN];
        float m = -1e30f;
        #pragma unroll
        for (int j = 0; j < NN; ++j) { v[j] = adj[tid * NN + j]; m = fmaxf(m, v[j]); }
        float s = 0.f;
        #pragma unroll
        for (int j = 0; j < NN; ++j) { v[j] = expf(v[j] - m); s += v[j]; }
        float rc = 1.f / s;
        #pragma unroll
        for (int j = 0; j < NN; ++j) A_g[tid * NN + j] = v[j] * rc;
    }
    if (tid >= 64 && tid < 64 + CCH) {
        int c = tid - 64;
        float inv = bn_gamma[c] * rsqrtf(bn_var[c] + 1e-5f);
        bnS[c] = inv;
        bnB[c] = conv_b[c] * inv + bn_beta[c] - bn_mean[c] * inv;
    }
}

// ---------------------------------------------------------------------------
// P2: Kronecker matrix m2g[c][k] = A[n,j]*gcn_w[o,f], c=(n*16+o) in [0,320)
// ---------------------------------------------------------------------------
__global__ __launch_bounds__(256) void prep_m2(
    const float* __restrict__ A_g, const float* __restrict__ gcn_w,
    __bf16* __restrict__ m2g)
{
    int i = blockIdx.x * 256 + threadIdx.x;
    if (i >= GW * KP) return;
    int c = i / KP, k = i - c * KP;
    float v = 0.f;
    if (c < NOUT && k < KC) {
        int n = c >> 4, o = c & 15;
        int j = k >> 3, f = k & 7;
        v = A_g[n * NN + j] * gcn_w[o * NF + f];
    }
    m2g[i] = (__bf16)v;
}

// ---------------------------------------------------------------------------
// A: conv(k5 depthwise)+bias+BN+ReLU+maxpool4 -> H2[j][row][8] bf16.
//    R9 structure (proven best) + float4 x reads (proven in R11-R13):
//    3 aligned vec loads + 2 edge selects replace 9 bounds-checked scalars.
// ---------------------------------------------------------------------------
__global__ __launch_bounds__(128) void conv_pool(
    const float* __restrict__ x,       // [NB][NN][TLEN]
    const float* __restrict__ conv_w,  // [CCH][5]
    const float* __restrict__ bnS, const float* __restrict__ bnB,
    __bf16* __restrict__ H)            // [NJP][NROWS][8]
{
    const int bid = blockIdx.x;
    const int b = bid / NN, n = bid - b * NN;
    const int tp = threadIdx.x;

    const float* xr = x + ((size_t)b * NN + n) * TLEN;
    const float4 f4z = {0.f, 0.f, 0.f, 0.f};
    float4 L0 = (tp > 0)   ? *(const float4*)(xr + 4 * tp - 4) : f4z;
    float4 L1 =              *(const float4*)(xr + 4 * tp);
    float4 L2 = (tp < 127) ? *(const float4*)(xr + 4 * tp + 4) : f4z;
    float xv[9] = {L0.z, L0.w, L1.x, L1.y, L1.z, L1.w, L2.x, L2.y, L2.z};

    const float* cw = conv_w + n * (NF * 5);
    const float* Sp = bnS + n * NF;
    const float* Bp = bnB + n * NF;

    union { __bf16 h[8]; u16x8 v; } hv;
    #pragma unroll
    for (int f = 0; f < NF; ++f) {
        float w0 = cw[f*5+0], w1 = cw[f*5+1], w2 = cw[f*5+2], w3 = cw[f*5+3], w4 = cw[f*5+4];
        float s = Sp[f], bb = Bp[f];
        float m = -1e30f;
        #pragma unroll
        for (int p = 0; p < 4; ++p) {
            float a = xv[p]*w0 + xv[p+1]*w1 + xv[p+2]*w2 + xv[p+3]*w3 + xv[p+4]*w4;
            m = fmaxf(m, a * s + bb);
        }
        hv.h[f] = (__bf16)fmaxf(m, 0.f);
    }
    size_t row = (size_t)b * TP + tp;
    *(u16x8*)(H + ((size_t)n * NROWS + row) * 8) = hv.v;
    if (n == NN - 1) {                         // zero plane j=19 (K pad)
        u16x8 z = {0,0,0,0,0,0,0,0};
        *(u16x8*)(H + ((size_t)(NJP - 1) * NROWS + row) * 8) = z;
    }
}

// ---------------------------------------------------------------------------
// B: MFMA contraction (C^T form) g2 = relu(H @ m2^T + gcn_b).
//    R9 v2 (proven): ZERO LDS, ZERO barriers; 25 m2 fragments in VGPRs
//    loaded once per block from L2; 8 row-tiles of 16; direct bf16x4
//    full-sector stores.
// ---------------------------------------------------------------------------
__global__ __launch_bounds__(256) void mix_gcn(
    const __bf16* __restrict__ H,      // [NJP][NROWS][8]
    const __bf16* __restrict__ m2g,    // [GW][KP]
    const float* __restrict__ gcn_b,   // [GO]
    __bf16* __restrict__ g2)           // [NROWS][GW]
{
    const int tid  = threadIdx.x;
    const int lane = tid & 63, w = tid >> 6;
    const int arow = lane & 15;
    const int jg   = lane >> 4;           // 0..3
    const int ct0  = w * 5;               // wave's first ct-tile (of 20)

    const float4 gbv = *(const float4*)(gcn_b + jg * 4);

    bf16x8 mf[5][5];
    #pragma unroll
    for (int ct = 0; ct < 5; ++ct)
        #pragma unroll
        for (int ks = 0; ks < 5; ++ks)
            mf[ct][ks] = *(const bf16x8*)(
                m2g + (size_t)((ct0 + ct) * 16 + arow) * KP + ks * 32 + jg * 8);

    const int Rbase = blockIdx.x * 128;
    for (int it = 0; it < 8; ++it) {
        const int R0 = Rbase + it * 16;

        const __bf16* hp = H + (size_t)(R0 + arow) * 8;
        bf16x8 af[5];
        #pragma unroll
        for (int ks = 0; ks < 5; ++ks)
            af[ks] = *(const bf16x8*)(hp + (size_t)(ks * 4 + jg) * NROWS * 8);

        f32x4 acc[5];
        #pragma unroll
        for (int ct = 0; ct < 5; ++ct) acc[ct] = (f32x4){0.f, 0.f, 0.f, 0.f};

        #pragma unroll
        for (int ks = 0; ks < 5; ++ks)
            #pragma unroll
            for (int ct = 0; ct < 5; ++ct)
                acc[ct] = __builtin_amdgcn_mfma_f32_16x16x32_bf16(mf[ct][ks], af[ks], acc[ct], 0, 0, 0);

        __bf16* gp = g2 + (size_t)(R0 + arow) * GW + ct0 * 16 + jg * 4;
        #pragma unroll
        for (int ct = 0; ct < 5; ++ct) {
            bf16x4 v;
            v[0] = (__bf16)fmaxf(acc[ct][0] + gbv.x, 0.f);
            v[1] = (__bf16)fmaxf(acc[ct][1] + gbv.y, 0.f);
            v[2] = (__bf16)fmaxf(acc[ct][2] + gbv.z, 0.f);
            v[3] = (__bf16)fmaxf(acc[ct][3] + gbv.w, 0.f);
            *(bf16x4*)(gp + ct * 16) = v;
        }
    }
}

// ---------------------------------------------------------------------------
// W: permute+convert w1 -> w1p[j][t*320 + c] bf16 (c=(n*16+o); pad cols 0)
// ---------------------------------------------------------------------------
__global__ __launch_bounds__(256) void w1_permute(
    const float* __restrict__ w1, __bf16* __restrict__ w1p)
{
    int i = blockIdx.x * 256 + threadIdx.x;    // chunk: j*5120 + t*40 + c8
    if (i >= HID * (KW / 8)) return;
    int j = i / 5120, rem = i - j * 5120;
    int t = rem / 40, c8 = rem - t * 40;
    bf16x8 r;
    if (c8 < 38) {
        int n = c8 >> 1, o0 = (c8 & 1) * 8;
        const float* src = w1 + (size_t)j * KFLAT + n * 2048 + t * 16 + o0;
        #pragma unroll
        for (int e = 0; e < 8; ++e) r[e] = (__bf16)src[e];
    } else {
        #pragma unroll
        for (int e = 0; e < 8; ++e) r[e] = (__bf16)0.f;
    }
    *(bf16x8*)(w1p + (size_t)i * 8) = r;
}

// ---------------------------------------------------------------------------
// G: split-K bf16 MFMA GEMM: partial[kt][b][j] = sum_k g2[b][k]*w1p[j][k]
// ---------------------------------------------------------------------------
__global__ __launch_bounds__(256) void gemm_fc1(
    const __bf16* __restrict__ gmat,   // [NB][KW]
    const __bf16* __restrict__ wmat,   // [HID][KW]
    float* __restrict__ partial)       // [NKT][NB][HID]
{
    __shared__ __align__(16) __bf16 At[128][40];
    __shared__ __align__(16) __bf16 Bt[128][40];

    const int tid = threadIdx.x;
    const int b0 = blockIdx.x * 128;
    const int k0 = blockIdx.y * KTILE;

    const int lane = tid & 63;
    const int w = tid >> 6;
    const int wm = (w >> 1) * 64;
    const int wn = (w & 1) * 64;

    const int srow = tid >> 2;
    const int soct = tid & 3;

    f32x4 acc[4][4];
    #pragma unroll
    for (int m = 0; m < 4; ++m)
        #pragma unroll
        for (int n = 0; n < 4; ++n) acc[m][n] = (f32x4){0.f, 0.f, 0.f, 0.f};

    const int arow = lane & 15;
    const int aoct = (lane >> 4) * 8;

    for (int ks = 0; ks < KTILE / 32; ++ks) {
        const int gk = k0 + ks * 32 + soct * 8;
        *(u16x8*)&At[srow     ][soct * 8] = *(const u16x8*)(gmat + (size_t)(b0 + srow     ) * KW + gk);
        *(u16x8*)&At[srow + 64][soct * 8] = *(const u16x8*)(gmat + (size_t)(b0 + srow + 64) * KW + gk);
        *(u16x8*)&Bt[srow     ][soct * 8] = *(const u16x8*)(wmat + (size_t)(srow     ) * KW + gk);
        *(u16x8*)&Bt[srow + 64][soct * 8] = *(const u16x8*)(wmat + (size_t)(srow + 64) * KW + gk);
        __syncthreads();

        bf16x8 af[4], bfr[4];
        #pragma unroll
        for (int m = 0; m < 4; ++m) af[m]  = *(const bf16x8*)&At[wm + m * 16 + arow][aoct];
        #pragma unroll
        for (int n = 0; n < 4; ++n) bfr[n] = *(const bf16x8*)&Bt[wn + n * 16 + arow][aoct];
        #pragma unroll
        for (int m = 0; m < 4; ++m)
            #pragma unroll
            for (int n = 0; n < 4; ++n)
                acc[m][n] = __builtin_amdgcn_mfma_f32_16x16x32_bf16(af[m], bfr[n], acc[m][n], 0, 0, 0);
        __syncthreads();
    }

    float* pout = partial + (size_t)blockIdx.y * (NB * HID);
    #pragma unroll
    for (int m = 0; m < 4; ++m) {
        const int rbase = b0 + wm + m * 16 + (lane >> 4) * 4;
        #pragma unroll
        for (int n = 0; n < 4; ++n) {
            const int col = wn + n * 16 + (lane & 15);
            #pragma unroll
            for (int r = 0; r < 4; ++r)
                pout[(size_t)(rbase + r) * HID + col] = acc[m][n][r];
        }
    }
}

// ---------------------------------------------------------------------------
// R: reduce split-K partials + b1 + ReLU, then FC2 (128->2) + b2
// ---------------------------------------------------------------------------
__global__ __launch_bounds__(128) void reduce_fc2(
    const float* __restrict__ partial,  // [NKT][NB][HID]
    const float* __restrict__ b1,
    const float* __restrict__ w2,       // [NCLS][HID]
    const float* __restrict__ b2,
    float* __restrict__ out)            // [NB][NCLS]
{
    __shared__ float red0[128], red1[128];
    const int b = blockIdx.x, j = threadIdx.x;
    float s = b1[j];
    #pragma unroll 4
    for (int p = 0; p < NKT; ++p) s += partial[(size_t)p * (NB * HID) + b * HID + j];
    float h = fmaxf(s, 0.f);
    red0[j] = h * w2[j];
    red1[j] = h * w2[HID + j];
    __syncthreads();
    for (int off = 64; off > 0; off >>= 1) {
        if (j < off) { red0[j] += red0[j + off]; red1[j] += red1[j + off]; }
        __syncthreads();
    }
    if (j == 0) {
        out[b * 2 + 0] = red0[0] + b2[0];
        out[b * 2 + 1] = red1[0] + b2[1];
    }
}

// ---------------------------------------------------------------------------
extern "C" void kernel_launch(void* const* d_in, const int* in_sizes, int n_in,
                              void* d_out, int out_size, void* d_ws, size_t ws_size,
                              hipStream_t stream) {
    const float* x        = (const float*)d_in[0];
    const float* conv_w   = (const float*)d_in[1];
    const float* conv_b   = (const float*)d_in[2];
    const float* bn_gamma = (const float*)d_in[3];
    const float* bn_beta  = (const float*)d_in[4];
    const float* bn_mean  = (const float*)d_in[5];
    const float* bn_var   = (const float*)d_in[6];
    const float* adj      = (const float*)d_in[7];
    const float* gcn_w    = (const float*)d_in[8];
    const float* gcn_b    = (const float*)d_in[9];
    const float* w1       = (const float*)d_in[10];
    const float* b1       = (const float*)d_in[11];
    const float* w2       = (const float*)d_in[12];
    const float* b2       = (const float*)d_in[13];
    float* out = (float*)d_out;

    // workspace (lifetime-overlapped, ~125.9 MB) — R9 layout:
    //   g2   [0,           83,886,080)   mix_gcn -> gemm_fc1
    //   H2   [83,886,080, 125,829,120)   conv_pool -> mix_gcn, then DEAD:
    //     w1p  [83,886,080, 94,371,840)  w1_permute (after mix_gcn) -> gemm
    //     part [94,371,840, 115,343,360) gemm -> reduce
    //   m2g  [125,829,120, 125,931,520)  prep_m2 -> mix_gcn
    //   A_g/bnS/bnB small after that
    char* ws = (char*)d_ws;
    __bf16* g2   = (__bf16*)ws;
    __bf16* Hbuf = (__bf16*)(ws + 83886080);
    __bf16* w1p  = (__bf16*)(ws + 83886080);
    float*  part = (float*)(ws + 94371840);
    __bf16* m2g  = (__bf16*)(ws + 125829120);
    float*  A_g  = (float*)(ws + 125931520);
    float*  bnS  = (float*)(ws + 125933568);
    float*  bnB  = (float*)(ws + 125934592);

    prep_small<<<dim3(1), dim3(256), 0, stream>>>(
        adj, bn_gamma, bn_beta, bn_mean, bn_var, conv_b, A_g, bnS, bnB);
    prep_m2<<<dim3(200), dim3(256), 0, stream>>>(A_g, gcn_w, m2g);
    conv_pool<<<dim3(NB * NN), dim3(128), 0, stream>>>(x, conv_w, bnS, bnB, Hbuf);
    mix_gcn<<<dim3(NROWS / 128), dim3(256), 0, stream>>>(Hbuf, m2g, gcn_b, g2);
    w1_permute<<<dim3(HID * (KW / 8) / 256), dim3(256), 0, stream>>>(w1, w1p);
    gemm_fc1<<<dim3(8, NKT), dim3(256), 0, stream>>>(g2, w1p, part);
    reduce_fc2<<<dim3(NB), dim3(128), 0, stream>>>(part, b1, w2, b2, out);
}